// Round 15
// baseline (97.199 us; speedup 1.0000x reference)
//
#include <hip/hip_runtime.h>

// Problem constants: x [B=1,T=8,C=32,D=32,H=64,W=64] fp32
constexpr int NT = 8;    // B*T
constexpr int C  = 32;
constexpr int D  = 32;
constexpr int H  = 64;
constexpr int W  = 64;   // == wavefront size: W-conv via lane shuffles
constexpr int ROWS = 4;  // h rows per block (one per wave)
constexpr int SP = D * H * W;       // per-channel spatial size = 131072
constexpr int HW = H * W;           // d-plane stride = 4096 elements

typedef unsigned int u32;

// bf16 RNE pack / unpack (validated rounds 3/9/12: absmax 0.0078 << 0.039)
static __device__ __forceinline__ u32 f2bf(float f) {
    u32 u = __float_as_uint(f);
    return (u + 0x7fffu + ((u >> 16) & 1u)) >> 16;
}
static __device__ __forceinline__ float bf_lo(u32 v) { return __uint_as_float(v << 16); }
static __device__ __forceinline__ float bf_hi(u32 v) { return __uint_as_float(v & 0xffff0000u); }

// ---------------------------------------------------------------------------
// Kernel A: fused depthwise chain, LDS-free (R12 structure, measured ~34 us),
// storing h as PACKED bf16 d-pairs into workspace (write bytes halved).
//   h = zconv3(x)+bz ; h = hconv3(h)+bx ; h = wconv3(h)+by ; 3x: h = zconv5_dil2(h)+bs
// One wave per (n,c,h) row; lane = w; thread owns the full D=32 column.
// Boundary bias semantics: a later conv's out-of-image tap drops its whole
// term (incl. earlier biases) — clamped row address + zeroed tap weight
// (term enters as wxk*(zconv+bz), so wxk=0 is exact).
// ---------------------------------------------------------------------------
__global__ __launch_bounds__(256, 4)
void dw_chain(const float* __restrict__ x,
              const float* __restrict__ w0z, const float* __restrict__ b0z,
              const float* __restrict__ w0x, const float* __restrict__ b0x,
              const float* __restrict__ w0y, const float* __restrict__ b0y,
              const float* __restrict__ wsz, const float* __restrict__ bsz,
              u32* __restrict__ hws)
{
    // XCD-chunk swizzle: 4096 blocks, 8 XCDs, chunk = 512 => XCD k owns one n
    // entirely: halo-row re-reads stay in that XCD's L2.
    const int rr  = blockIdx.x;
    const int lid = (rr & 7) * (NT * C * (H / ROWS) / 8) + (rr >> 3);
    const int htile = lid % (H / ROWS);
    const int c     = (lid / (H / ROWS)) % C;
    const int n     = lid / ((H / ROWS) * C);

    const int tid = threadIdx.x;
    const int w   = tid & 63;                              // lane (divergent)
    const int hg  = __builtin_amdgcn_readfirstlane(htile * ROWS + (tid >> 6));

    const float* xc = x + ((size_t)n * C + c) * SP;

    // Per-channel weights (block-uniform -> scalar regs)
    const float wz0 = w0z[c*3+0], wz1 = w0z[c*3+1], wz2 = w0z[c*3+2];
    const float wx1 = w0x[c*3+1];
    const float wy0 = w0y[c*3+0], wy1 = w0y[c*3+1], wy2 = w0y[c*3+2];
    const float bz = b0z[c], bx = b0x[c], by = b0y[c], bs = bsz[c];
    float wsk[5];
    #pragma unroll
    for (int k = 0; k < 5; ++k) wsk[k] = wsz[c*5+k];

    // Boundary: clamp row index (legal load), zero the tap weight (exact).
    const float wxk0 = (hg > 0)     ? w0x[c*3+0] : 0.f;
    const float wxk2 = (hg < H - 1) ? w0x[c*3+2] : 0.f;
    const int   hm = (hg > 0)     ? hg - 1 : 0;
    const int   hp = (hg < H - 1) ? hg + 1 : H - 1;

    // Scalar row base pointers (SGPR); only +w is vector.
    const float* p0 = xc + (size_t)hm * W;
    const float* p1 = xc + (size_t)hg * W;
    const float* p2 = xc + (size_t)hp * W;

    // ---- loads + h-conv (along H) ----------------------------------------
    float hrow[D];
    #pragma unroll
    for (int d = 0; d < D; ++d) {
        const float a0 = p0[(size_t)d * HW + w];
        const float a1 = p1[(size_t)d * HW + w];
        const float a2 = p2[(size_t)d * HW + w];
        hrow[d] = wxk0 * a0 + wx1 * a1 + wxk2 * a2;
    }

    // ---- z-conv (along D) + folded biases --------------------------------
    const float cb = bx + (wxk0 + wx1 + wxk2) * bz;
    float acc2[D];
    #pragma unroll
    for (int d = 0; d < D; ++d) {
        float t = cb + wz1 * hrow[d];
        if (d > 0)     t += wz0 * hrow[d - 1];
        if (d < D - 1) t += wz2 * hrow[d + 1];
        acc2[d] = t;
    }

    // ---- w-conv via lane shuffles (W == 64 == wavefront) -----------------
    const bool has_l = (w > 0), has_r = (w < W - 1);
    float acc3[D];
    #pragma unroll
    for (int d = 0; d < D; ++d) {
        float left  = __shfl_up(acc2[d], 1);
        float right = __shfl_down(acc2[d], 1);
        float t = by + wy1 * acc2[d];
        if (has_l) t += wy0 * left;
        if (has_r) t += wy2 * right;
        acc3[d] = t;
    }

    // ---- three 5-tap dilation-2 convs along D (pad 4), in registers ------
    #pragma unroll
    for (int it = 0; it < 3; ++it) {
        float s[D];
        #pragma unroll
        for (int d = 0; d < D; ++d) {
            float t = bs;
            #pragma unroll
            for (int k = 0; k < 5; ++k) {
                int j = d + 2 * k - 4;
                if (j >= 0 && j < D) t += wsk[k] * acc3[j];
            }
            s[d] = t;
        }
        #pragma unroll
        for (int d = 0; d < D; ++d) acc3[d] = s[d];
    }

    // ---- store packed bf16 d-pairs (thread-local pack, no shuffles) ------
    // layout: hws[((n*C+c)*(D/2) + k)*HW + hg*W + w], coalesced across lanes
    u32* hc = hws + ((size_t)(n * C + c) * (D / 2)) * HW + (size_t)hg * W;
    #pragma unroll
    for (int k = 0; k < D / 2; ++k)
        hc[(size_t)k * HW + w] = f2bf(acc3[2*k]) | (f2bf(acc3[2*k+1]) << 16);
}

// ---------------------------------------------------------------------------
// Kernel B: pointwise 1x1x1 conv + residual multiply.
// Reads packed-bf16 h from d_ws (L3/L2-hot from dw), reads x (L3-resident),
// writes fp32 out with NONTEMPORAL stores (no write-allocate, no L3
// pollution — the R14-proven property). R15 change: co-loop unrolled x4 ->
// ~8 independent loads + 8 NT stores in flight (was ~4), attacking the
// last latency exposure.
// ---------------------------------------------------------------------------
__global__ __launch_bounds__(256)
void pw_mul(const float* __restrict__ x,
            const u32* __restrict__ hws,
            const float* __restrict__ wp, const float* __restrict__ bp,
            float* __restrict__ out)
{
    // XCD alignment: n = blockIdx&7 matches dw's swizzle (XCD k owns n=k)
    const int b    = blockIdx.x;
    const int n    = b & 7;
    const int pid  = (b >> 3) * 256 + threadIdx.x;   // (dp, h, w) within n
    const int dp   = pid >> 12;                      // d-pair 0..15
    const int sphw = pid & 4095;                     // h*64 + w

    const u32* hp = hws + ((size_t)(n * C) * (D / 2) + dp) * HW + sphw;

    float v0[C], v1[C];
    #pragma unroll
    for (int ci = 0; ci < C; ++ci) {
        const u32 u = hp[(size_t)ci * (D / 2) * HW];
        v0[ci] = bf_lo(u);
        v1[ci] = bf_hi(u);
    }

    const size_t i0base = (size_t)n * C * SP + (size_t)(2 * dp) * HW + sphw;

    #pragma unroll 4
    for (int co = 0; co < C; ++co) {
        float y0 = bp[co], y1 = bp[co];
        #pragma unroll
        for (int ci = 0; ci < C; ++ci) {
            const float wv = wp[co * C + ci];
            y0 += wv * v0[ci];
            y1 += wv * v1[ci];
        }
        const size_t ia = i0base + (size_t)co * SP;
        const size_t ib = ia + (size_t)HW;
        __builtin_nontemporal_store(x[ia] * y0, &out[ia]);
        __builtin_nontemporal_store(x[ib] * y1, &out[ib]);
    }
}

extern "C" void kernel_launch(void* const* d_in, const int* in_sizes, int n_in,
                              void* d_out, int out_size, void* d_ws, size_t ws_size,
                              hipStream_t stream)
{
    const float* x   = (const float*)d_in[0];
    const float* w0z = (const float*)d_in[1];
    const float* b0z = (const float*)d_in[2];
    const float* w0x = (const float*)d_in[3];
    const float* b0x = (const float*)d_in[4];
    const float* w0y = (const float*)d_in[5];
    const float* b0y = (const float*)d_in[6];
    const float* wsz = (const float*)d_in[7];
    const float* bsz = (const float*)d_in[8];
    const float* wp  = (const float*)d_in[9];
    const float* bp  = (const float*)d_in[10];
    float* out = (float*)d_out;
    u32* hws = (u32*)d_ws;               // 16.8M words = 67 MB of workspace

    // Kernel A: depthwise chain -> packed bf16 h in workspace
    const int gridA = NT * C * (H / ROWS);        // 4096 blocks, 256 thr
    dw_chain<<<gridA, 256, 0, stream>>>(x, w0z, b0z, w0x, b0x, w0y, b0y,
                                        wsz, bsz, hws);

    // Kernel B: pointwise + residual -> out (nontemporal, unroll 4)
    const int gridB = NT * (D / 2) * HW / 256;    // 2048 blocks
    pw_mul<<<gridB, 256, 0, stream>>>(x, hws, wp, bp, out);
}

// Round 16
// 91.743 us; speedup vs baseline: 1.0595x; 1.0595x over previous
//
#include <hip/hip_runtime.h>

// Problem constants: x [B=1,T=8,C=32,D=32,H=64,W=64] fp32
constexpr int NT = 8;    // B*T
constexpr int C  = 32;
constexpr int D  = 32;
constexpr int H  = 64;
constexpr int W  = 64;   // == wavefront size: W-conv via lane shuffles
constexpr int ROWS = 4;  // h rows per block (one per wave)
constexpr int SP = D * H * W;       // per-channel spatial size = 131072
constexpr int HW = H * W;           // d-plane stride = 4096 elements

typedef unsigned int u32;

// bf16 RNE pack / unpack (validated rounds 3/9/12: absmax 0.0078 << 0.039)
static __device__ __forceinline__ u32 f2bf(float f) {
    u32 u = __float_as_uint(f);
    return (u + 0x7fffu + ((u >> 16) & 1u)) >> 16;
}
static __device__ __forceinline__ float bf_lo(u32 v) { return __uint_as_float(v << 16); }
static __device__ __forceinline__ float bf_hi(u32 v) { return __uint_as_float(v & 0xffff0000u); }

// ---------------------------------------------------------------------------
// Kernel A: fused depthwise chain, LDS-free (R12 structure, measured ~34 us),
// storing h as PACKED bf16 d-pairs into workspace (write bytes halved).
//   h = zconv3(x)+bz ; h = hconv3(h)+bx ; h = wconv3(h)+by ; 3x: h = zconv5_dil2(h)+bs
// One wave per (n,c,h) row; lane = w; thread owns the full D=32 column.
// Boundary bias semantics: a later conv's out-of-image tap drops its whole
// term (incl. earlier biases) — clamped row address + zeroed tap weight
// (term enters as wxk*(zconv+bz), so wxk=0 is exact).
// ---------------------------------------------------------------------------
__global__ __launch_bounds__(256, 4)
void dw_chain(const float* __restrict__ x,
              const float* __restrict__ w0z, const float* __restrict__ b0z,
              const float* __restrict__ w0x, const float* __restrict__ b0x,
              const float* __restrict__ w0y, const float* __restrict__ b0y,
              const float* __restrict__ wsz, const float* __restrict__ bsz,
              u32* __restrict__ hws)
{
    // XCD-chunk swizzle: 4096 blocks, 8 XCDs, chunk = 512 => XCD k owns one n
    // entirely: halo-row re-reads stay in that XCD's L2.
    const int rr  = blockIdx.x;
    const int lid = (rr & 7) * (NT * C * (H / ROWS) / 8) + (rr >> 3);
    const int htile = lid % (H / ROWS);
    const int c     = (lid / (H / ROWS)) % C;
    const int n     = lid / ((H / ROWS) * C);

    const int tid = threadIdx.x;
    const int w   = tid & 63;                              // lane (divergent)
    const int hg  = __builtin_amdgcn_readfirstlane(htile * ROWS + (tid >> 6));

    const float* xc = x + ((size_t)n * C + c) * SP;

    // Per-channel weights (block-uniform -> scalar regs)
    const float wz0 = w0z[c*3+0], wz1 = w0z[c*3+1], wz2 = w0z[c*3+2];
    const float wx1 = w0x[c*3+1];
    const float wy0 = w0y[c*3+0], wy1 = w0y[c*3+1], wy2 = w0y[c*3+2];
    const float bz = b0z[c], bx = b0x[c], by = b0y[c], bs = bsz[c];
    float wsk[5];
    #pragma unroll
    for (int k = 0; k < 5; ++k) wsk[k] = wsz[c*5+k];

    // Boundary: clamp row index (legal load), zero the tap weight (exact).
    const float wxk0 = (hg > 0)     ? w0x[c*3+0] : 0.f;
    const float wxk2 = (hg < H - 1) ? w0x[c*3+2] : 0.f;
    const int   hm = (hg > 0)     ? hg - 1 : 0;
    const int   hp = (hg < H - 1) ? hg + 1 : H - 1;

    // Scalar row base pointers (SGPR); only +w is vector.
    const float* p0 = xc + (size_t)hm * W;
    const float* p1 = xc + (size_t)hg * W;
    const float* p2 = xc + (size_t)hp * W;

    // ---- loads + h-conv (along H) ----------------------------------------
    float hrow[D];
    #pragma unroll
    for (int d = 0; d < D; ++d) {
        const float a0 = p0[(size_t)d * HW + w];
        const float a1 = p1[(size_t)d * HW + w];
        const float a2 = p2[(size_t)d * HW + w];
        hrow[d] = wxk0 * a0 + wx1 * a1 + wxk2 * a2;
    }

    // ---- z-conv (along D) + folded biases --------------------------------
    const float cb = bx + (wxk0 + wx1 + wxk2) * bz;
    float acc2[D];
    #pragma unroll
    for (int d = 0; d < D; ++d) {
        float t = cb + wz1 * hrow[d];
        if (d > 0)     t += wz0 * hrow[d - 1];
        if (d < D - 1) t += wz2 * hrow[d + 1];
        acc2[d] = t;
    }

    // ---- w-conv via lane shuffles (W == 64 == wavefront) -----------------
    const bool has_l = (w > 0), has_r = (w < W - 1);
    float acc3[D];
    #pragma unroll
    for (int d = 0; d < D; ++d) {
        float left  = __shfl_up(acc2[d], 1);
        float right = __shfl_down(acc2[d], 1);
        float t = by + wy1 * acc2[d];
        if (has_l) t += wy0 * left;
        if (has_r) t += wy2 * right;
        acc3[d] = t;
    }

    // ---- three 5-tap dilation-2 convs along D (pad 4), in registers ------
    #pragma unroll
    for (int it = 0; it < 3; ++it) {
        float s[D];
        #pragma unroll
        for (int d = 0; d < D; ++d) {
            float t = bs;
            #pragma unroll
            for (int k = 0; k < 5; ++k) {
                int j = d + 2 * k - 4;
                if (j >= 0 && j < D) t += wsk[k] * acc3[j];
            }
            s[d] = t;
        }
        #pragma unroll
        for (int d = 0; d < D; ++d) acc3[d] = s[d];
    }

    // ---- store packed bf16 d-pairs (thread-local pack, no shuffles) ------
    // layout: hws[((n*C+c)*(D/2) + k)*HW + hg*W + w], coalesced across lanes
    u32* hc = hws + ((size_t)(n * C + c) * (D / 2)) * HW + (size_t)hg * W;
    #pragma unroll
    for (int k = 0; k < D / 2; ++k)
        hc[(size_t)k * HW + w] = f2bf(acc3[2*k]) | (f2bf(acc3[2*k+1]) << 16);
}

// ---------------------------------------------------------------------------
// Kernel B: pointwise 1x1x1 conv + residual multiply.
// Reads packed-bf16 h from d_ws (L3-dirty-resident from dw), reads x
// (L3-resident in steady state), writes fp32 out with NONTEMPORAL stores:
// no write-allocate, no L3 pollution -> L3 holds exactly x(134)+h(67)=201 MB
// < 256 MB, and the 134 MB out stream goes straight to HBM at fill-kernel
// rates. unroll 2 = measured optimum (R14 92.7 us; unroll 4 regressed).
// ---------------------------------------------------------------------------
__global__ __launch_bounds__(256)
void pw_mul(const float* __restrict__ x,
            const u32* __restrict__ hws,
            const float* __restrict__ wp, const float* __restrict__ bp,
            float* __restrict__ out)
{
    // XCD alignment: n = blockIdx&7 matches dw's swizzle (XCD k owns n=k)
    const int b    = blockIdx.x;
    const int n    = b & 7;
    const int pid  = (b >> 3) * 256 + threadIdx.x;   // (dp, h, w) within n
    const int dp   = pid >> 12;                      // d-pair 0..15
    const int sphw = pid & 4095;                     // h*64 + w

    const u32* hp = hws + ((size_t)(n * C) * (D / 2) + dp) * HW + sphw;

    float v0[C], v1[C];
    #pragma unroll
    for (int ci = 0; ci < C; ++ci) {
        const u32 u = hp[(size_t)ci * (D / 2) * HW];
        v0[ci] = bf_lo(u);
        v1[ci] = bf_hi(u);
    }

    const size_t i0base = (size_t)n * C * SP + (size_t)(2 * dp) * HW + sphw;

    #pragma unroll 2
    for (int co = 0; co < C; ++co) {
        float y0 = bp[co], y1 = bp[co];
        #pragma unroll
        for (int ci = 0; ci < C; ++ci) {
            const float wv = wp[co * C + ci];
            y0 += wv * v0[ci];
            y1 += wv * v1[ci];
        }
        const size_t ia = i0base + (size_t)co * SP;
        const size_t ib = ia + (size_t)HW;
        __builtin_nontemporal_store(x[ia] * y0, &out[ia]);
        __builtin_nontemporal_store(x[ib] * y1, &out[ib]);
    }
}

extern "C" void kernel_launch(void* const* d_in, const int* in_sizes, int n_in,
                              void* d_out, int out_size, void* d_ws, size_t ws_size,
                              hipStream_t stream)
{
    const float* x   = (const float*)d_in[0];
    const float* w0z = (const float*)d_in[1];
    const float* b0z = (const float*)d_in[2];
    const float* w0x = (const float*)d_in[3];
    const float* b0x = (const float*)d_in[4];
    const float* w0y = (const float*)d_in[5];
    const float* b0y = (const float*)d_in[6];
    const float* wsz = (const float*)d_in[7];
    const float* bsz = (const float*)d_in[8];
    const float* wp  = (const float*)d_in[9];
    const float* bp  = (const float*)d_in[10];
    float* out = (float*)d_out;
    u32* hws = (u32*)d_ws;               // 16.8M words = 67 MB of workspace

    // Kernel A: depthwise chain -> packed bf16 h in workspace
    const int gridA = NT * C * (H / ROWS);        // 4096 blocks, 256 thr
    dw_chain<<<gridA, 256, 0, stream>>>(x, w0z, b0z, w0x, b0x, w0y, b0y,
                                        wsz, bsz, hws);

    // Kernel B: pointwise + residual -> out (nontemporal, unroll 2)
    const int gridB = NT * (D / 2) * HW / 256;    // 2048 blocks
    pw_mul<<<gridB, 256, 0, stream>>>(x, hws, wp, bp, out);
}